// Round 1
// baseline (171.546 us; speedup 1.0000x reference)
//
#include <hip/hip_runtime.h>

// SpectralRegularizer closed form (see analysis):
//   All k_mag fall in searchsorted bin 1 -> spectrum = [0, S1, 0...0] (len 32)
//   S1 = sum_{b,c} E_rfft / (128*128*65 * 4)
//   E_rfft(slice) = (128^3 * sum x^2 + 128^2 * (sum A^2 + sum B^2)) / 2
//     A[x,y] = sum_z x[x,y,z];  B[x,y] = sum_z (-1)^z x[x,y,z]
//   out = 0.01 * decay_const + 0.001 * S1/31
//   decay_const = mean_{k=9..31} (k^{-5/3} / (9^{-5/3}+1e-8))^2   (data-independent)

#define N_ROWPAIRS (12 * 128 * 128 / 2)   // (b*c*X*Y) rows of 128, in pairs

__global__ void spectral_reduce(const float* __restrict__ x, double* __restrict__ acc) {
    // acc[0] += sum x^2 ; acc[1] += sum over rows (rowsum^2 + rowalt^2)
    const int lane   = threadIdx.x & 63;
    const int waveId = (blockIdx.x * blockDim.x + threadIdx.x) >> 6;
    const int nWaves = (gridDim.x * blockDim.x) >> 6;

    float acc_sq = 0.0f;      // every lane accumulates its own x^2 partial
    float acc_pl = 0.0f;      // only lanes 0 and 32 accumulate row results

    for (int p = waveId; p < N_ROWPAIRS; p += nWaves) {
        // one wave covers 2 contiguous rows = 256 floats; lane loads float4
        const float4 w = ((const float4*)(x + (size_t)p * 256))[lane];
        float s = w.x + w.y + w.z + w.w;          // row sum piece
        float a = w.x - w.y + w.z - w.w;          // (-1)^z row sum piece
        acc_sq += w.x * w.x + w.y * w.y + w.z * w.z + w.w * w.w;
        // reduce s,a within each 32-lane half (one half per row)
        #pragma unroll
        for (int off = 1; off < 32; off <<= 1) {
            s += __shfl_xor(s, off, 64);
            a += __shfl_xor(a, off, 64);
        }
        if ((lane & 31) == 0) acc_pl += s * s + a * a;
    }

    // full-wave reduce both accumulators
    #pragma unroll
    for (int off = 1; off < 64; off <<= 1) {
        acc_sq += __shfl_xor(acc_sq, off, 64);
        acc_pl += __shfl_xor(acc_pl, off, 64);
    }

    __shared__ float s_sq[8], s_pl[8];
    const int w = threadIdx.x >> 6;
    if (lane == 0) { s_sq[w] = acc_sq; s_pl[w] = acc_pl; }
    __syncthreads();
    if (threadIdx.x == 0) {
        float tsq = 0.0f, tpl = 0.0f;
        const int nw = blockDim.x >> 6;
        for (int i = 0; i < nw; ++i) { tsq += s_sq[i]; tpl += s_pl[i]; }
        atomicAdd(&acc[0], (double)tsq);   // f64 global atomic (CDNA HW)
        atomicAdd(&acc[1], (double)tpl);
    }
}

__global__ void spectral_finalize(const double* __restrict__ acc, float* __restrict__ out) {
    const double sum_sq = acc[0];
    const double plane  = acc[1];
    const double E  = (2097152.0 * sum_sq + 16384.0 * plane) * 0.5;  // 128^3, 128^2
    const double S1 = E / (128.0 * 128.0 * 65.0 * 4.0);
    const double cascade = S1 / 31.0;

    const double slope = -5.0 / 3.0;
    const double e0 = pow(9.0, slope) + 1e-8;
    double ss = 0.0;
    for (int k = 9; k < 32; ++k) {
        const double en = pow((double)k, slope) / e0;
        ss += en * en;
    }
    const double decay = ss / 23.0;

    out[0] = (float)(0.01 * decay + 0.001 * cascade);
}

extern "C" void kernel_launch(void* const* d_in, const int* in_sizes, int n_in,
                              void* d_out, int out_size, void* d_ws, size_t ws_size,
                              hipStream_t stream) {
    const float* x  = (const float*)d_in[0];
    double* acc     = (double*)d_ws;
    float* out      = (float*)d_out;

    hipMemsetAsync(acc, 0, 2 * sizeof(double), stream);   // ws is re-poisoned 0xAA
    spectral_reduce<<<1024, 256, 0, stream>>>(x, acc);
    spectral_finalize<<<1, 1, 0, stream>>>(acc, out);
}

// Round 2
// 153.617 us; speedup vs baseline: 1.1167x; 1.1167x over previous
//
#include <hip/hip_runtime.h>

// SpectralRegularizer closed form (verified exact in R1, absmax 0.0):
//   All k_mag fall in searchsorted bin 1 -> spectrum = [0, S1, 0...0] (len 32)
//   S1 = sum_{b,c} E_rfft / (128*128*65 * 4)
//   E_rfft(slice) = (128^3 * sum x^2 + 128^2 * (sum A^2 + sum B^2)) / 2
//     A[x,y] = sum_z x[x,y,z];  B[x,y] = sum_z (-1)^z x[x,y,z]
//   out = 0.01 * decay_const + 0.001 * S1/31
//   decay_const = mean_{k=9..31} (k^{-5/3} / (9^{-5/3}+1e-8))^2  (data-independent)
//
// R2 structure: no memset, no atomics. Kernel1 overwrites per-block partials
// (d_ws), kernel2 (single block) reduces partials + emits the scalar.

#define NBLOCKS    1024
#define N_ROWPAIRS (12 * 128 * 128 / 2)   // (b*c*X*Y) rows of 128, in pairs

__global__ __launch_bounds__(256) void spectral_reduce(
        const float* __restrict__ x, double* __restrict__ partials) {
    // partials[b]          = block b's sum x^2
    // partials[NBLOCKS+b]  = block b's sum over rows (rowsum^2 + rowalt^2)
    const int lane   = threadIdx.x & 63;
    const int waveId = (blockIdx.x * blockDim.x + threadIdx.x) >> 6;
    const int nWaves = (gridDim.x * blockDim.x) >> 6;

    float acc_sq = 0.0f;      // every lane: own x^2 partial
    float acc_pl = 0.0f;      // lanes 0,32: row results

    for (int p = waveId; p < N_ROWPAIRS; p += nWaves) {
        // one wave covers 2 contiguous rows = 256 floats; lane loads float4
        const float4 w = ((const float4*)(x + (size_t)p * 256))[lane];
        float s = w.x + w.y + w.z + w.w;          // row sum piece
        float a = w.x - w.y + w.z - w.w;          // (-1)^z row sum piece
        acc_sq += w.x * w.x + w.y * w.y + w.z * w.z + w.w * w.w;
        // reduce s,a within each 32-lane half (one half per row)
        #pragma unroll
        for (int off = 1; off < 32; off <<= 1) {
            s += __shfl_xor(s, off, 64);
            a += __shfl_xor(a, off, 64);
        }
        if ((lane & 31) == 0) acc_pl += s * s + a * a;
    }

    // full-wave reduce both accumulators
    #pragma unroll
    for (int off = 1; off < 64; off <<= 1) {
        acc_sq += __shfl_xor(acc_sq, off, 64);
        acc_pl += __shfl_xor(acc_pl, off, 64);
    }

    __shared__ float s_sq[4], s_pl[4];
    const int w = threadIdx.x >> 6;
    if (lane == 0) { s_sq[w] = acc_sq; s_pl[w] = acc_pl; }
    __syncthreads();
    if (threadIdx.x == 0) {
        float tsq = 0.0f, tpl = 0.0f;
        #pragma unroll
        for (int i = 0; i < 4; ++i) { tsq += s_sq[i]; tpl += s_pl[i]; }
        partials[blockIdx.x]           = (double)tsq;   // plain store, no init needed
        partials[NBLOCKS + blockIdx.x] = (double)tpl;
    }
}

__global__ __launch_bounds__(1024) void spectral_finalize(
        const double* __restrict__ partials, float* __restrict__ out) {
    const int tid  = threadIdx.x;
    const int lane = tid & 63;

    double sq = partials[tid];
    double pl = partials[NBLOCKS + tid];
    #pragma unroll
    for (int off = 1; off < 64; off <<= 1) {
        sq += __shfl_xor(sq, off, 64);
        pl += __shfl_xor(pl, off, 64);
    }

    __shared__ double w_sq[16], w_pl[16];
    const int w = tid >> 6;
    if (lane == 0) { w_sq[w] = sq; w_pl[w] = pl; }
    __syncthreads();

    if (tid == 0) {
        double sum_sq = 0.0, plane = 0.0;
        #pragma unroll
        for (int i = 0; i < 16; ++i) { sum_sq += w_sq[i]; plane += w_pl[i]; }

        const double E  = (2097152.0 * sum_sq + 16384.0 * plane) * 0.5;  // 128^3, 128^2
        const double S1 = E / (128.0 * 128.0 * 65.0 * 4.0);
        const double cascade = S1 / 31.0;

        const double slope = -5.0 / 3.0;
        const double e0 = pow(9.0, slope) + 1e-8;
        double ss = 0.0;
        for (int k = 9; k < 32; ++k) {
            const double en = pow((double)k, slope) / e0;
            ss += en * en;
        }
        const double decay = ss / 23.0;

        out[0] = (float)(0.01 * decay + 0.001 * cascade);
    }
}

extern "C" void kernel_launch(void* const* d_in, const int* in_sizes, int n_in,
                              void* d_out, int out_size, void* d_ws, size_t ws_size,
                              hipStream_t stream) {
    const float* x    = (const float*)d_in[0];
    double* partials  = (double*)d_ws;    // 2*NBLOCKS doubles = 16 KB, fully overwritten
    float* out        = (float*)d_out;

    spectral_reduce<<<NBLOCKS, 256, 0, stream>>>(x, partials);
    spectral_finalize<<<1, 1024, 0, stream>>>(partials, out);
}